// Round 8
// baseline (316.878 us; speedup 1.0000x reference)
//
#include <hip/hip_runtime.h>
#include <hip/hip_fp16.h>

#define F 64
#define CHUNK 2048    // edges per chunk (256 thr x 2 int4 x 4)
#define BN 512        // dst nodes per bucket (power of 2)
#define BSHIFT 9
#define MAXB 11264    // fixed csr region per bucket (slots); bucket max ~10.3K (17 sigma)
// record = (dstLocal<<17)|src : needs n < 2^17 (n=100000 ok)

typedef int v4i __attribute__((ext_vector_type(4)));
typedef float fx4 __attribute__((ext_vector_type(4)));
typedef float v2f __attribute__((ext_vector_type(2)));
typedef _Float16 h8f __attribute__((ext_vector_type(8)));

union FB8 { uint4 u; h8f h; };
union FX4P { fx4 v; v2f p[2]; };

// ============ per-chunk bucket histogram (int4 edge reads, LDS atomics) ============
__global__ __launch_bounds__(256) void k_blkcnt(const int* __restrict__ dst,
                                                int* __restrict__ blkcnt,
                                                int E, int NB, int NBKT) {
    __shared__ int lcnt[256];
    int b = blockIdx.x, t = threadIdx.x;
    lcnt[t] = 0;
    __syncthreads();
    const v4i* d4 = (const v4i*)dst;
    int g0 = (b * CHUNK) >> 2;
    int E4 = E >> 2;   // E divisible by 4 for this problem
#pragma unroll
    for (int k = 0; k < 2; ++k) {
        int gi = g0 + k * 256 + t;
        if (gi < E4) {
            v4i q = __builtin_nontemporal_load(d4 + gi);
            atomicAdd(&lcnt[q.x >> BSHIFT], 1);
            atomicAdd(&lcnt[q.y >> BSHIFT], 1);
            atomicAdd(&lcnt[q.z >> BSHIFT], 1);
            atomicAdd(&lcnt[q.w >> BSHIFT], 1);
        }
    }
    __syncthreads();
    if (t < NBKT) blkcnt[t * NB + b] = lcnt[t];
}

// ============ per-bucket scan over chunk counts -> blkoff, bkttot ============
__global__ __launch_bounds__(256) void k_bktscan(const int* __restrict__ blkcnt,
                                                 int* __restrict__ blkoff,
                                                 int* __restrict__ bkttot, int NB) {
    __shared__ int s[256];
    __shared__ int running;
    int seg = blockIdx.x;
    int t = threadIdx.x;
    if (t == 0) running = 0;
    __syncthreads();
    for (int base = 0; base < NB; base += 256) {
        int i = base + t;
        int v = (i < NB) ? blkcnt[seg * NB + i] : 0;
        s[t] = v;
        __syncthreads();
        for (int off = 1; off < 256; off <<= 1) {
            int x = (t >= off) ? s[t - off] : 0;
            __syncthreads();
            s[t] += x;
            __syncthreads();
        }
        int rbase = running;
        if (i < NB) blkoff[seg * NB + i] = rbase + s[t] - v;
        int ctot = s[255];
        __syncthreads();
        if (t == 0) running = rbase + ctot;
        __syncthreads();
    }
    if (t == 0) bkttot[seg] = running;
}

// ============ chunk -> bucket-sorted staging; sb scan INLINED (kills k_sb bubble) ============
__global__ __launch_bounds__(256) void k_stage2(const int* __restrict__ src,
                                                const int* __restrict__ dst,
                                                const int* __restrict__ blkoff,
                                                const int* __restrict__ bkttot,
                                                unsigned* __restrict__ stage,
                                                int E, int NB, int NBKT) {
    __shared__ int lcnt[256];
    __shared__ int lbase[257];
    __shared__ int obase[256];
    __shared__ int s[256];
    __shared__ unsigned rec[CHUNK];
    __shared__ unsigned char binof[CHUNK];
    int b = blockIdx.x, t = threadIdx.x;
    lcnt[t] = 0;
    __syncthreads();
    const v4i* d4 = (const v4i*)dst;
    const v4i* s4 = (const v4i*)src;
    int g0 = (b * CHUNK) >> 2;
    int E4 = E >> 2;
    int myseg[8], myrank[8];
    unsigned myrec[8];
#pragma unroll
    for (int k = 0; k < 2; ++k) {
        int gi = g0 + k * 256 + t;
        bool ok = gi < E4;
        v4i qd = {0, 0, 0, 0}, qs = {0, 0, 0, 0};
        if (ok) {
            qd = __builtin_nontemporal_load(d4 + gi);
            qs = __builtin_nontemporal_load(s4 + gi);
        }
        int dd[4] = {qd.x, qd.y, qd.z, qd.w};
        int ss[4] = {qs.x, qs.y, qs.z, qs.w};
#pragma unroll
        for (int j = 0; j < 4; ++j) {
            int idx = k * 4 + j;
            myseg[idx] = -1;
            if (ok) {
                int sg = dd[j] >> BSHIFT;
                myseg[idx] = sg;
                myrank[idx] = atomicAdd(&lcnt[sg], 1);
                myrec[idx] = ((unsigned)(dd[j] & (BN - 1)) << 17) | (unsigned)ss[j];
            }
        }
    }
    __syncthreads();
    int v = lcnt[t];
    s[t] = v;
    __syncthreads();
    for (int off = 1; off < 256; off <<= 1) {
        int x = (t >= off) ? s[t - off] : 0;
        __syncthreads();
        s[t] += x;
        __syncthreads();
    }
    lbase[t] = s[t] - v;
    if (t == 255) lbase[256] = s[255];
    // inline exclusive scan of bkttot -> obase (replaces k_sb + sb[] round-trip)
    int bv = (t < NBKT) ? bkttot[t] : 0;
    __syncthreads();
    s[t] = bv;
    __syncthreads();
    for (int off = 1; off < 256; off <<= 1) {
        int x = (t >= off) ? s[t - off] : 0;
        __syncthreads();
        s[t] += x;
        __syncthreads();
    }
    obase[t] = (t < NBKT) ? (s[t] - bv) + blkoff[t * NB + b] : 0;
    __syncthreads();
#pragma unroll
    for (int k = 0; k < 8; ++k) {
        if (myseg[k] >= 0) {
            int p = lbase[myseg[k]] + myrank[k];
            rec[p] = myrec[k];
            binof[p] = (unsigned char)myseg[k];
        }
    }
    __syncthreads();
    int tot = lbase[256];
    for (int j = t; j < tot; j += 256) {
        int sg = binof[j];
        stage[obase[sg] + (j - lbase[sg])] = rec[j];
    }
}

// ============ FUSED: histogram + dis + row_start + csr fill + fp16 prep ============
// Replaces k_bincount + k_sb2 + k_binfill + k_prep (2 launches were 1-block
// bubbles). Fixed per-bucket csr regions (bkt*MAXB) remove the cross-bucket
// scan; k_layer computes hi = lo + pad4(count) so region gaps are invisible.
// Also converts this bucket's x rows to fp16(dis*x) (dis fresh in LDS) and
// zeroes row n of both buffers (last bucket).
__global__ __launch_bounds__(512) void k_bins(const unsigned* __restrict__ stage,
        const int* __restrict__ bkttot, const float4* __restrict__ x4,
        int* __restrict__ count, int* __restrict__ row_start,
        float* __restrict__ dis, int* __restrict__ csr,
        uint2* __restrict__ hs, uint2* __restrict__ hs2, int n, int NBKT) {
    __shared__ int s[256];
    __shared__ int sbv[257];
    __shared__ int lc[BN];
    __shared__ int sc[BN];
    __shared__ float fdis[BN];
    __shared__ int buf[MAXB];
    int bkt = blockIdx.x, t = threadIdx.x;
    int nb0 = bkt << BSHIFT;
    // exclusive scan of bkttot (196 vals) -> sbv[0..NBKT]
    int bv = 0;
    if (t < 256) { bv = (t < NBKT) ? bkttot[t] : 0; s[t] = bv; }
    __syncthreads();
    for (int off = 1; off < 256; off <<= 1) {
        int x = (t < 256 && t >= off) ? s[t - off] : 0;
        __syncthreads();
        if (t < 256) s[t] += x;
        __syncthreads();
    }
    if (t < 256) { sbv[t] = s[t] - bv; if (t == 255) sbv[256] = s[255]; }
    lc[t] = 0;
    __syncthreads();
    int r0 = sbv[bkt], r1 = sbv[bkt + 1];
    // histogram
    for (int j = r0 + t; j < r1; j += 512) atomicAdd(&lc[stage[j] >> 17], 1);
    __syncthreads();
    int node = nb0 + t;
    int cv = lc[t];
    int pv = 0;
    float dval = 0.f;
    if (node < n) {
        count[node] = cv;
        dval = rsqrtf((float)(cv + 1));
        dis[node] = dval;
        pv = (cv + 3) & ~3;
    }
    fdis[t] = dval;
    sc[t] = pv;
    __syncthreads();
    for (int off = 1; off < BN; off <<= 1) {
        int x = (t >= off) ? sc[t - off] : 0;
        __syncthreads();
        sc[t] += x;
        __syncthreads();
    }
    int excl = sc[t] - pv;
    int wlen = sc[BN - 1];
    if (node < n) row_start[node] = bkt * MAXB + excl;
    lc[t] = excl;                         // reuse as fill cursor
    for (int j = t; j < wlen && j < MAXB; j += 512) buf[j] = n;   // pad value
    __syncthreads();
    for (int j = r0 + t; j < r1; j += 512) {
        unsigned r = stage[j];
        int p = atomicAdd(&lc[r >> 17], 1);
        if (p < MAXB) buf[p] = (int)(r & 0x1FFFFu);
    }
    __syncthreads();
    int cbase = bkt * MAXB;
    for (int j = t; j < wlen && j < MAXB; j += 512) csr[cbase + j] = buf[j];
    // fp16 prep for this bucket's rows (+ row n of both buffers in last bucket)
    for (int ii = t; ii < (BN << 4); ii += 512) {
        int loc = ii >> 4;
        int node2 = nb0 + loc;
        int c = ii & 15;
        float dv = 0.f;
        float4 v = make_float4(0.f, 0.f, 0.f, 0.f);
        if (node2 < n) { dv = fdis[loc]; v = x4[(size_t)node2 * 16 + c]; }
        __half2 h01 = __floats2half2_rn(dv * v.x, dv * v.y);
        __half2 h23 = __floats2half2_rn(dv * v.z, dv * v.w);
        uint2 u;
        u.x = *(unsigned*)&h01;
        u.y = *(unsigned*)&h23;
        if (node2 <= n) hs[(size_t)node2 * 16 + c] = u;
        if (node2 == n) hs2[(size_t)n * 16 + c] = make_uint2(0u, 0u);
    }
}

// ============ direct-B MFMA aggregation (depth-3 prefetch) + exact f32 transform ============
// r7 post-mortem: conflicts gone, time unchanged -> memory-side plateau ~2TB/s
// L2-miss traffic. Depth-3 tests latency-vs-BW: 3 frag sets + 3-reg node
// rotation (+16 VGPR). hi = lo + pad4(count) (fixed-region csr). Everything
// else identical to the verified r7 kernel.
__global__ __launch_bounds__(256) void k_layer(const __half* __restrict__ hin,
        const float* __restrict__ W, const float* __restrict__ b,
        const int* __restrict__ row_start, const int* __restrict__ count,
        const int* __restrict__ csr, const float* __restrict__ dis,
        __half* __restrict__ hout, int n, int scale_out) {
    __shared__ char lds_all[16384];
    int tid = threadIdx.x;
    int lane = tid & 63;
    int wv = tid >> 6;
    int r0 = (blockIdx.x * 4 + wv) << 4;
    if (r0 >= n) return;
    char* myLds = lds_all + (wv << 12);
    const _Float16* hp = (const _Float16*)hin;

    int r_  = lane & 15;
    int g4  = lane >> 4;
    int l31 = lane & 31;

    int lo = row_start[r0 + r_];
    int cnt_ = count[r0 + r_];
    int hi = lo + ((cnt_ + 3) & ~3);
    int s0 = __shfl(lo, 0);
    int s4 = __shfl(hi, 15);
    int NBb = (s4 - s0 + 31) >> 5;      // 32-slot batches; batch NBb = self
    unsigned deg = (unsigned)(hi - lo);

    fx4 acc0 = {0.f, 0.f, 0.f, 0.f};
    fx4 acc1 = acc0, acc2 = acc0, acc3 = acc0;

    // nodes for batch i: lane holds node of slot (l&31)
    auto ldnodes = [&](int i) -> int {
        if (i < NBb) {
            int slot = s0 + (i << 5) + l31;
            int nd = csr[slot];                 // slack in csr alloc; value clamped
            return (slot < s4) ? nd : n;
        }
        return (l31 < 16) ? (r0 + l31) : n;     // self batch (q>=16 -> zero row)
    };

#define LOADFRAG(F0, F1, F2, F3, NDS) { \
    _Pragma("unroll") \
    for (int j = 0; j < 8; ++j) { \
        int ndj = __shfl((NDS), 8 * g4 + j); \
        const _Float16* rp = hp + (((size_t)(unsigned)ndj) << 6) + r_; \
        F0.h[j] = rp[0]; \
        F1.h[j] = rp[16]; \
        F2.h[j] = rp[32]; \
        F3.h[j] = rp[48]; \
    } \
}

#define SMFMA(TT, F0, F1, F2, F3) { \
    unsigned w[4]; \
    if ((TT) < NBb) { \
        unsigned u0 = (unsigned)(s0 + ((TT) << 5) + (g4 << 3)) - (unsigned)lo; \
        w[0] = ((u0     ) < deg ? 0x3C00u : 0u) | ((u0 + 1u) < deg ? 0x3C000000u : 0u); \
        w[1] = ((u0 + 2u) < deg ? 0x3C00u : 0u) | ((u0 + 3u) < deg ? 0x3C000000u : 0u); \
        w[2] = ((u0 + 4u) < deg ? 0x3C00u : 0u) | ((u0 + 5u) < deg ? 0x3C000000u : 0u); \
        w[3] = ((u0 + 6u) < deg ? 0x3C00u : 0u) | ((u0 + 7u) < deg ? 0x3C000000u : 0u); \
    } else { \
        int k0 = g4 << 3; \
        w[0] = ((k0    ) == r_ ? 0x3C00u : 0u) | ((k0 + 1) == r_ ? 0x3C000000u : 0u); \
        w[1] = ((k0 + 2) == r_ ? 0x3C00u : 0u) | ((k0 + 3) == r_ ? 0x3C000000u : 0u); \
        w[2] = ((k0 + 4) == r_ ? 0x3C00u : 0u) | ((k0 + 5) == r_ ? 0x3C000000u : 0u); \
        w[3] = ((k0 + 6) == r_ ? 0x3C00u : 0u) | ((k0 + 7) == r_ ? 0x3C000000u : 0u); \
    } \
    FB8 af; af.u = make_uint4(w[0], w[1], w[2], w[3]); \
    acc0 = __builtin_amdgcn_mfma_f32_16x16x32_f16(af.h, F0.h, acc0, 0, 0, 0); \
    acc1 = __builtin_amdgcn_mfma_f32_16x16x32_f16(af.h, F1.h, acc1, 0, 0, 0); \
    acc2 = __builtin_amdgcn_mfma_f32_16x16x32_f16(af.h, F2.h, acc2, 0, 0, 0); \
    acc3 = __builtin_amdgcn_mfma_f32_16x16x32_f16(af.h, F3.h, acc3, 0, 0, 0); \
}

    FB8 A0, A1, A2, A3, B0, B1, B2, B3, C0, C1, C2, C3;
    int ndX, ndY, ndZ;
    {
        int nd = ldnodes(0);
        LOADFRAG(A0, A1, A2, A3, nd)       // B(0)
        nd = ldnodes(1);
        LOADFRAG(B0, B1, B2, B3, nd)       // B(1)
        ndX = ldnodes(2); ndY = ldnodes(3); ndZ = ldnodes(4);
    }

    for (int t = 0; ; t += 3) {
        LOADFRAG(C0, C1, C2, C3, ndX)      // B(t+2)
        ndX = ldnodes(t + 5);
        SMFMA(t, A0, A1, A2, A3)
        if (t + 1 > NBb) break;
        LOADFRAG(A0, A1, A2, A3, ndY)      // B(t+3)
        ndY = ldnodes(t + 6);
        SMFMA(t + 1, B0, B1, B2, B3)
        if (t + 2 > NBb) break;
        LOADFRAG(B0, B1, B2, B3, ndZ)      // B(t+4)
        ndZ = ldnodes(t + 7);
        SMFMA(t + 2, C0, C1, C2, C3)
        if (t + 3 > NBb) break;
    }
#undef LOADFRAG
#undef SMFMA

    // ---- dump acc (f32, exact) to T[64 f][16 r]; lane holds D[4g4+v][16S+r_] ----
    float* T = (float*)myLds;
#define TSTORE(S, A) { \
    int fb_ = ((16 * (S) + r_) << 4) + (g4 << 2); \
    *(fx4*)(T + fb_) = A; }
    TSTORE(0, acc0) TSTORE(1, acc1) TSTORE(2, acc2) TSTORE(3, acc3)
#undef TSTORE

    // ---- exact f32 transform (pk-fma): lane = output column o, 16 rows ----
    float bb_ = b[lane];
    v2f yv2[8];
#pragma unroll
    for (int k = 0; k < 8; ++k) { yv2[k].x = 0.f; yv2[k].y = 0.f; }
    const float* Wp = W + lane;
#pragma unroll 4
    for (int f = 0; f < 64; ++f) {
        float w = Wp[f << 6];                   // W[f][lane], coalesced
        v2f wv; wv.x = w; wv.y = w;
        const float* Tf = T + (f << 4);
        FX4P d0, d1, d2, d3;
        d0.v = *(const fx4*)(Tf);               // uniform addr -> LDS broadcast
        d1.v = *(const fx4*)(Tf + 4);
        d2.v = *(const fx4*)(Tf + 8);
        d3.v = *(const fx4*)(Tf + 12);
        yv2[0] += d0.p[0] * wv;  yv2[1] += d0.p[1] * wv;
        yv2[2] += d1.p[0] * wv;  yv2[3] += d1.p[1] * wv;
        yv2[4] += d2.p[0] * wv;  yv2[5] += d2.p[1] * wv;
        yv2[6] += d3.p[0] * wv;  yv2[7] += d3.p[1] * wv;
    }

#pragma unroll
    for (int r = 0; r < 16; ++r) {
        float yvr = (r & 1) ? yv2[r >> 1].y : yv2[r >> 1].x;
        float dd = dis[r0 + r];
        float y = fmaxf(yvr * dd + bb_, 0.f);
        if (scale_out) y *= dd;
        hout[((size_t)(r0 + r) << 6) + lane] = __float2half(y);
    }
}

// ============ final 64->8 linear: row-per-thread, uint2 vector loads ============
__global__ __launch_bounds__(256) void k_final(const __half* __restrict__ h,
                                               const float* __restrict__ Wl,
                                               const float* __restrict__ bl,
                                               float* __restrict__ out, int n) {
    __shared__ float Ws[F * 8];
    __shared__ float bs[8];
    int tid = threadIdx.x;
    Ws[tid] = Wl[tid];
    Ws[tid + 256] = Wl[tid + 256];
    if (tid < 8) bs[tid] = bl[tid];
    __syncthreads();
    int row = blockIdx.x * 256 + tid;
    if (row >= n) return;
    const uint2* hr = (const uint2*)(h + (size_t)row * F);
    float acc[8];
#pragma unroll
    for (int o = 0; o < 8; ++o) acc[o] = bs[o];
#pragma unroll
    for (int k4 = 0; k4 < 16; ++k4) {
        uint2 u = hr[k4];
        float2 f01 = __half22float2(*(__half2*)&u.x);
        float2 f23 = __half22float2(*(__half2*)&u.y);
        const float* w0 = Ws + (k4 * 4) * 8;
#pragma unroll
        for (int o = 0; o < 8; ++o) {
            float a = acc[o];
            a = fmaf(f01.x, w0[o], a);
            a = fmaf(f01.y, w0[8 + o], a);
            a = fmaf(f23.x, w0[16 + o], a);
            a = fmaf(f23.y, w0[24 + o], a);
            acc[o] = a;
        }
    }
    float4* op = (float4*)(out + (size_t)row * 8);
    op[0] = make_float4(acc[0], acc[1], acc[2], acc[3]);
    op[1] = make_float4(acc[4], acc[5], acc[6], acc[7]);
}

extern "C" void kernel_launch(void* const* d_in, const int* in_sizes, int n_in,
                              void* d_out, int out_size, void* d_ws, size_t ws_size,
                              hipStream_t stream) {
    const float* x  = (const float*)d_in[0];
    const int*   ei = (const int*)d_in[1];
    const float* W1 = (const float*)d_in[2];
    const float* b1 = (const float*)d_in[3];
    const float* W2 = (const float*)d_in[4];
    const float* b2 = (const float*)d_in[5];
    const float* W3 = (const float*)d_in[6];
    const float* b3 = (const float*)d_in[7];
    const float* Wl = (const float*)d_in[8];
    const float* bl = (const float*)d_in[9];
    float* out = (float*)d_out;

    int n = in_sizes[0] / F;   // 100000 (n % 16 == 0, n < 2^17)
    int E = in_sizes[1] / 2;   // 1600000 (divisible by 4)
    const int* src = ei;
    const int* dst = ei + E;

    int np   = (n + 256) & ~255;              // >= n+1, multiple of 256
    int NB   = (E + CHUNK - 1) / CHUNK;       // 782 chunks
    int NBKT = (n + BN - 1) >> BSHIFT;        // 196 buckets (<=256)

    // workspace layout (~44 MB)
    int*      count     = (int*)d_ws;
    int*      row_start = count + np;
    int*      blkcnt    = row_start + np;       // 256*NB
    int*      blkoff    = blkcnt + 256 * NB;
    int*      bkttot    = blkoff + 256 * NB;    // 256 -> pad 272
    float*    dis       = (float*)(bkttot + 272);
    unsigned* stage     = (unsigned*)(dis + np);  // E records (4 B each)
    int*      csr       = (int*)(stage + ((E + 3) & ~3));   // NBKT*MAXB + slack
    __half*   buf1      = (__half*)(csr + NBKT * MAXB + 64);
    __half*   buf2      = buf1 + (size_t)(n + 1) * F;

    // ---- bucket histogram (one dst pass; NO global atomics; int4 reads) ----
    k_blkcnt<<<NB, 256, 0, stream>>>(dst, blkcnt, E, NB, NBKT);

    // ---- bucket-sorted staging (sb scan inlined) ----
    k_bktscan<<<NBKT, 256, 0, stream>>>(blkcnt, blkoff, bkttot, NB);
    k_stage2<<<NB, 256, 0, stream>>>(src, dst, blkoff, bkttot, stage, E, NB, NBKT);

    // ---- fused: counts + dis + row_start + csr fill + fp16 prep ----
    k_bins<<<NBKT, 512, 0, stream>>>(stage, bkttot, (const float4*)x, count,
                                     row_start, dis, csr, (uint2*)buf1,
                                     (uint2*)buf2, n, NBKT);

    // ---- 3 fused layers (direct-B gather, depth-3 prefetch) ----
    int nb_l = (n + 63) / 64;   // 4 waves/block, 16 rows/wave
    k_layer<<<nb_l, 256, 0, stream>>>(buf1, W1, b1, row_start, count, csr, dis, buf2, n, 1);
    k_layer<<<nb_l, 256, 0, stream>>>(buf2, W2, b2, row_start, count, csr, dis, buf1, n, 1);
    k_layer<<<nb_l, 256, 0, stream>>>(buf1, W3, b3, row_start, count, csr, dis, buf2, n, 0);

    // ---- final linear (row-per-thread, vectorized) ----
    k_final<<<(n + 255) / 256, 256, 0, stream>>>(buf2, Wl, bl, out, n);
}

// Round 9
// 311.355 us; speedup vs baseline: 1.0177x; 1.0177x over previous
//
#include <hip/hip_runtime.h>
#include <hip/hip_fp16.h>

#define F 64
#define CHUNK 2048    // edges per chunk (256 thr x 2 int4 x 4)
#define BN 512        // dst nodes per bucket (power of 2)
#define BSHIFT 9
#define MAXBS 10240   // fixed stage region per bucket (edges); mean 8192, +22 sigma
#define MAXB 11264    // fixed csr region per bucket (padded slots); max ~10.8K
// record = (dstLocal<<17)|src : needs n < 2^17 (n=100000 ok)

typedef int v4i __attribute__((ext_vector_type(4)));
typedef float fx4 __attribute__((ext_vector_type(4)));
typedef float v2f __attribute__((ext_vector_type(2)));
typedef _Float16 h8f __attribute__((ext_vector_type(8)));

union FB8 { uint4 u; h8f h; };
union FX4P { fx4 v; v2f p[2]; };

// ============ single-pass bucket-sorted staging ============
// Replaces k_blkcnt + k_bktscan + k_sb + old k_stage2 (two edge passes + scan
// kernels). Fixed per-bucket stage regions (bkt*MAXBS) + one global cursor
// atomicAdd per (block, nonzero bucket) -> block-local placement. Order within
// a bucket is arbitrary (aggregation is a sum).
__global__ __launch_bounds__(256) void k_stage(const int* __restrict__ src,
                                               const int* __restrict__ dst,
                                               int* __restrict__ gcur,
                                               unsigned* __restrict__ stage,
                                               int E, int NBKT) {
    __shared__ int lcnt[256];
    __shared__ int lbase[257];
    __shared__ int obase[256];
    __shared__ int s[256];
    __shared__ unsigned rec[CHUNK];
    __shared__ unsigned char binof[CHUNK];
    int b = blockIdx.x, t = threadIdx.x;
    lcnt[t] = 0;
    __syncthreads();
    const v4i* d4 = (const v4i*)dst;
    const v4i* s4 = (const v4i*)src;
    int g0 = (b * CHUNK) >> 2;
    int E4 = E >> 2;   // E divisible by 4
    int myseg[8], myrank[8];
    unsigned myrec[8];
#pragma unroll
    for (int k = 0; k < 2; ++k) {
        int gi = g0 + k * 256 + t;
        bool ok = gi < E4;
        v4i qd = {0, 0, 0, 0}, qs = {0, 0, 0, 0};
        if (ok) {
            qd = __builtin_nontemporal_load(d4 + gi);
            qs = __builtin_nontemporal_load(s4 + gi);
        }
        int dd[4] = {qd.x, qd.y, qd.z, qd.w};
        int ss[4] = {qs.x, qs.y, qs.z, qs.w};
#pragma unroll
        for (int j = 0; j < 4; ++j) {
            int idx = k * 4 + j;
            myseg[idx] = -1;
            if (ok) {
                int sg = dd[j] >> BSHIFT;
                myseg[idx] = sg;
                myrank[idx] = atomicAdd(&lcnt[sg], 1);
                myrec[idx] = ((unsigned)(dd[j] & (BN - 1)) << 17) | (unsigned)ss[j];
            }
        }
    }
    __syncthreads();
    int v = lcnt[t];
    s[t] = v;
    __syncthreads();
    for (int off = 1; off < 256; off <<= 1) {
        int x = (t >= off) ? s[t - off] : 0;
        __syncthreads();
        s[t] += x;
        __syncthreads();
    }
    lbase[t] = s[t] - v;
    if (t == 255) lbase[256] = s[255];
    obase[t] = 0;
    if (t < NBKT && v > 0) obase[t] = t * MAXBS + atomicAdd(&gcur[t], v);
    __syncthreads();
#pragma unroll
    for (int k = 0; k < 8; ++k) {
        if (myseg[k] >= 0) {
            int p = lbase[myseg[k]] + myrank[k];
            rec[p] = myrec[k];
            binof[p] = (unsigned char)myseg[k];
        }
    }
    __syncthreads();
    int tot = lbase[256];
    for (int j = t; j < tot; j += 256) {
        int sg = binof[j];
        stage[obase[sg] + (j - lbase[sg])] = rec[j];
    }
}

// ============ FUSED: histogram + dis + row_start + csr fill + fp16 prep ============
// Fixed regions both sides: stage[bkt*MAXBS .. +gcur[bkt]), csr[bkt*MAXB ...).
// k_layer computes hi = lo + pad4(count) so region gaps are invisible.
// Also converts this bucket's x rows to fp16(dis*x) and zeroes row n.
__global__ __launch_bounds__(512) void k_bins(const unsigned* __restrict__ stage,
        const int* __restrict__ gcur, const float4* __restrict__ x4,
        int* __restrict__ count, int* __restrict__ row_start,
        float* __restrict__ dis, int* __restrict__ csr,
        uint2* __restrict__ hs, uint2* __restrict__ hs2, int n) {
    __shared__ int lc[BN];
    __shared__ int sc[BN];
    __shared__ float fdis[BN];
    __shared__ int buf[MAXB];
    int bkt = blockIdx.x, t = threadIdx.x;
    int nb0 = bkt << BSHIFT;
    lc[t] = 0;
    __syncthreads();
    int r0 = bkt * MAXBS;
    int r1 = r0 + gcur[bkt];
    // histogram
    for (int j = r0 + t; j < r1; j += 512) atomicAdd(&lc[stage[j] >> 17], 1);
    __syncthreads();
    int node = nb0 + t;
    int cv = lc[t];
    int pv = 0;
    float dval = 0.f;
    if (node < n) {
        count[node] = cv;
        dval = rsqrtf((float)(cv + 1));
        dis[node] = dval;
        pv = (cv + 3) & ~3;
    }
    fdis[t] = dval;
    sc[t] = pv;
    __syncthreads();
    for (int off = 1; off < BN; off <<= 1) {
        int x = (t >= off) ? sc[t - off] : 0;
        __syncthreads();
        sc[t] += x;
        __syncthreads();
    }
    int excl = sc[t] - pv;
    int wlen = sc[BN - 1];
    if (node < n) row_start[node] = bkt * MAXB + excl;
    lc[t] = excl;                         // reuse as fill cursor
    for (int j = t; j < wlen && j < MAXB; j += 512) buf[j] = n;   // pad value
    __syncthreads();
    for (int j = r0 + t; j < r1; j += 512) {
        unsigned r = stage[j];
        int p = atomicAdd(&lc[r >> 17], 1);
        if (p < MAXB) buf[p] = (int)(r & 0x1FFFFu);
    }
    __syncthreads();
    int cbase = bkt * MAXB;
    for (int j = t; j < wlen && j < MAXB; j += 512) csr[cbase + j] = buf[j];
    // fp16 prep for this bucket's rows (+ row n of both buffers in last bucket)
    for (int ii = t; ii < (BN << 4); ii += 512) {
        int loc = ii >> 4;
        int node2 = nb0 + loc;
        int c = ii & 15;
        float dv = 0.f;
        float4 v = make_float4(0.f, 0.f, 0.f, 0.f);
        if (node2 < n) { dv = fdis[loc]; v = x4[(size_t)node2 * 16 + c]; }
        __half2 h01 = __floats2half2_rn(dv * v.x, dv * v.y);
        __half2 h23 = __floats2half2_rn(dv * v.z, dv * v.w);
        uint2 u;
        u.x = *(unsigned*)&h01;
        u.y = *(unsigned*)&h23;
        if (node2 <= n) hs[(size_t)node2 * 16 + c] = u;
        if (node2 == n) hs2[(size_t)n * 16 + c] = make_uint2(0u, 0u);
    }
}

// ============ direct-B MFMA aggregation (depth-2, r7-proven) + exact f32 transform ============
// r8 post-mortem: depth-3 blew the per-XCD L2 footprint (FETCH 81.6->150MB);
// depth-2 is the latency/locality equilibrium. Body identical to the verified
// r7 kernel; interface uses fixed-region csr + hi = lo + pad4(count) (r8-verified).
__global__ __launch_bounds__(256) void k_layer(const __half* __restrict__ hin,
        const float* __restrict__ W, const float* __restrict__ b,
        const int* __restrict__ row_start, const int* __restrict__ count,
        const int* __restrict__ csr, const float* __restrict__ dis,
        __half* __restrict__ hout, int n, int scale_out) {
    __shared__ char lds_all[16384];
    int tid = threadIdx.x;
    int lane = tid & 63;
    int wv = tid >> 6;
    int r0 = (blockIdx.x * 4 + wv) << 4;
    if (r0 >= n) return;
    char* myLds = lds_all + (wv << 12);
    const _Float16* hp = (const _Float16*)hin;

    int r_  = lane & 15;
    int g4  = lane >> 4;
    int l31 = lane & 31;

    int lo = row_start[r0 + r_];
    int cnt_ = count[r0 + r_];
    int hi = lo + ((cnt_ + 3) & ~3);
    int s0 = __shfl(lo, 0);
    int s4 = __shfl(hi, 15);
    int NBb = (s4 - s0 + 31) >> 5;      // 32-slot batches; batch NBb = self
    unsigned deg = (unsigned)(hi - lo);

    fx4 acc0 = {0.f, 0.f, 0.f, 0.f};
    fx4 acc1 = acc0, acc2 = acc0, acc3 = acc0;

    // nodes for batch i: lane holds node of slot (l&31)
    auto ldnodes = [&](int i) -> int {
        if (i < NBb) {
            int slot = s0 + (i << 5) + l31;
            int nd = csr[slot];                 // slack in csr alloc; value clamped
            return (slot < s4) ? nd : n;
        }
        return (l31 < 16) ? (r0 + l31) : n;     // self batch (q>=16 -> zero row)
    };

#define LOADFRAG(F0, F1, F2, F3, NDS) { \
    _Pragma("unroll") \
    for (int j = 0; j < 8; ++j) { \
        int ndj = __shfl((NDS), 8 * g4 + j); \
        const _Float16* rp = hp + (((size_t)(unsigned)ndj) << 6) + r_; \
        F0.h[j] = rp[0]; \
        F1.h[j] = rp[16]; \
        F2.h[j] = rp[32]; \
        F3.h[j] = rp[48]; \
    } \
}

#define SMFMA(TT, F0, F1, F2, F3) { \
    unsigned w[4]; \
    if ((TT) < NBb) { \
        unsigned u0 = (unsigned)(s0 + ((TT) << 5) + (g4 << 3)) - (unsigned)lo; \
        w[0] = ((u0     ) < deg ? 0x3C00u : 0u) | ((u0 + 1u) < deg ? 0x3C000000u : 0u); \
        w[1] = ((u0 + 2u) < deg ? 0x3C00u : 0u) | ((u0 + 3u) < deg ? 0x3C000000u : 0u); \
        w[2] = ((u0 + 4u) < deg ? 0x3C00u : 0u) | ((u0 + 5u) < deg ? 0x3C000000u : 0u); \
        w[3] = ((u0 + 6u) < deg ? 0x3C00u : 0u) | ((u0 + 7u) < deg ? 0x3C000000u : 0u); \
    } else { \
        int k0 = g4 << 3; \
        w[0] = ((k0    ) == r_ ? 0x3C00u : 0u) | ((k0 + 1) == r_ ? 0x3C000000u : 0u); \
        w[1] = ((k0 + 2) == r_ ? 0x3C00u : 0u) | ((k0 + 3) == r_ ? 0x3C000000u : 0u); \
        w[2] = ((k0 + 4) == r_ ? 0x3C00u : 0u) | ((k0 + 5) == r_ ? 0x3C000000u : 0u); \
        w[3] = ((k0 + 6) == r_ ? 0x3C00u : 0u) | ((k0 + 7) == r_ ? 0x3C000000u : 0u); \
    } \
    FB8 af; af.u = make_uint4(w[0], w[1], w[2], w[3]); \
    acc0 = __builtin_amdgcn_mfma_f32_16x16x32_f16(af.h, F0.h, acc0, 0, 0, 0); \
    acc1 = __builtin_amdgcn_mfma_f32_16x16x32_f16(af.h, F1.h, acc1, 0, 0, 0); \
    acc2 = __builtin_amdgcn_mfma_f32_16x16x32_f16(af.h, F2.h, acc2, 0, 0, 0); \
    acc3 = __builtin_amdgcn_mfma_f32_16x16x32_f16(af.h, F3.h, acc3, 0, 0, 0); \
}

    FB8 A0, A1, A2, A3, B0, B1, B2, B3;
    int ndA, ndB;
    {
        int nd0 = ldnodes(0);
        LOADFRAG(A0, A1, A2, A3, nd0)      // B(0)
        ndA = ldnodes(1);                  // nodes(t+1)
        ndB = ldnodes(2);                  // nodes(t+2)
    }

    for (int t = 0; ; t += 2) {
        LOADFRAG(B0, B1, B2, B3, ndA)      // issue B(t+1) gathers
        ndA = ldnodes(t + 3);
        SMFMA(t, A0, A1, A2, A3)
        if (t + 1 > NBb) break;
        LOADFRAG(A0, A1, A2, A3, ndB)      // issue B(t+2) gathers
        ndB = ldnodes(t + 4);
        SMFMA(t + 1, B0, B1, B2, B3)
        if (t + 2 > NBb) break;
    }
#undef LOADFRAG
#undef SMFMA

    // ---- dump acc (f32, exact) to T[64 f][16 r]; lane holds D[4g4+v][16S+r_] ----
    float* T = (float*)myLds;
#define TSTORE(S, A) { \
    int fb_ = ((16 * (S) + r_) << 4) + (g4 << 2); \
    *(fx4*)(T + fb_) = A; }
    TSTORE(0, acc0) TSTORE(1, acc1) TSTORE(2, acc2) TSTORE(3, acc3)
#undef TSTORE

    // ---- exact f32 transform (pk-fma): lane = output column o, 16 rows ----
    float bb_ = b[lane];
    v2f yv2[8];
#pragma unroll
    for (int k = 0; k < 8; ++k) { yv2[k].x = 0.f; yv2[k].y = 0.f; }
    const float* Wp = W + lane;
#pragma unroll 4
    for (int f = 0; f < 64; ++f) {
        float w = Wp[f << 6];                   // W[f][lane], coalesced
        v2f wv; wv.x = w; wv.y = w;
        const float* Tf = T + (f << 4);
        FX4P d0, d1, d2, d3;
        d0.v = *(const fx4*)(Tf);               // uniform addr -> LDS broadcast
        d1.v = *(const fx4*)(Tf + 4);
        d2.v = *(const fx4*)(Tf + 8);
        d3.v = *(const fx4*)(Tf + 12);
        yv2[0] += d0.p[0] * wv;  yv2[1] += d0.p[1] * wv;
        yv2[2] += d1.p[0] * wv;  yv2[3] += d1.p[1] * wv;
        yv2[4] += d2.p[0] * wv;  yv2[5] += d2.p[1] * wv;
        yv2[6] += d3.p[0] * wv;  yv2[7] += d3.p[1] * wv;
    }

#pragma unroll
    for (int r = 0; r < 16; ++r) {
        float yvr = (r & 1) ? yv2[r >> 1].y : yv2[r >> 1].x;
        float dd = dis[r0 + r];
        float y = fmaxf(yvr * dd + bb_, 0.f);
        if (scale_out) y *= dd;
        hout[((size_t)(r0 + r) << 6) + lane] = __float2half(y);
    }
}

// ============ final 64->8 linear: row-per-thread, uint2 vector loads ============
__global__ __launch_bounds__(256) void k_final(const __half* __restrict__ h,
                                               const float* __restrict__ Wl,
                                               const float* __restrict__ bl,
                                               float* __restrict__ out, int n) {
    __shared__ float Ws[F * 8];
    __shared__ float bs[8];
    int tid = threadIdx.x;
    Ws[tid] = Wl[tid];
    Ws[tid + 256] = Wl[tid + 256];
    if (tid < 8) bs[tid] = bl[tid];
    __syncthreads();
    int row = blockIdx.x * 256 + tid;
    if (row >= n) return;
    const uint2* hr = (const uint2*)(h + (size_t)row * F);
    float acc[8];
#pragma unroll
    for (int o = 0; o < 8; ++o) acc[o] = bs[o];
#pragma unroll
    for (int k4 = 0; k4 < 16; ++k4) {
        uint2 u = hr[k4];
        float2 f01 = __half22float2(*(__half2*)&u.x);
        float2 f23 = __half22float2(*(__half2*)&u.y);
        const float* w0 = Ws + (k4 * 4) * 8;
#pragma unroll
        for (int o = 0; o < 8; ++o) {
            float a = acc[o];
            a = fmaf(f01.x, w0[o], a);
            a = fmaf(f01.y, w0[8 + o], a);
            a = fmaf(f23.x, w0[16 + o], a);
            a = fmaf(f23.y, w0[24 + o], a);
            acc[o] = a;
        }
    }
    float4* op = (float4*)(out + (size_t)row * 8);
    op[0] = make_float4(acc[0], acc[1], acc[2], acc[3]);
    op[1] = make_float4(acc[4], acc[5], acc[6], acc[7]);
}

extern "C" void kernel_launch(void* const* d_in, const int* in_sizes, int n_in,
                              void* d_out, int out_size, void* d_ws, size_t ws_size,
                              hipStream_t stream) {
    const float* x  = (const float*)d_in[0];
    const int*   ei = (const int*)d_in[1];
    const float* W1 = (const float*)d_in[2];
    const float* b1 = (const float*)d_in[3];
    const float* W2 = (const float*)d_in[4];
    const float* b2 = (const float*)d_in[5];
    const float* W3 = (const float*)d_in[6];
    const float* b3 = (const float*)d_in[7];
    const float* Wl = (const float*)d_in[8];
    const float* bl = (const float*)d_in[9];
    float* out = (float*)d_out;

    int n = in_sizes[0] / F;   // 100000 (n % 16 == 0, n < 2^17)
    int E = in_sizes[1] / 2;   // 1600000 (divisible by 4)
    const int* src = ei;
    const int* dst = ei + E;

    int np   = (n + 256) & ~255;              // >= n+1, multiple of 256
    int NB   = (E + CHUNK - 1) / CHUNK;       // 782 chunks
    int NBKT = (n + BN - 1) >> BSHIFT;        // 196 buckets (<=256)

    // workspace layout (~44 MB)
    int*      count     = (int*)d_ws;
    int*      row_start = count + np;
    int*      gcur      = row_start + np;       // 196 -> pad 272
    float*    dis       = (float*)(gcur + 272);
    unsigned* stage     = (unsigned*)(dis + np);  // NBKT*MAXBS
    int*      csr       = (int*)(stage + NBKT * MAXBS);   // NBKT*MAXB + slack
    __half*   buf1      = (__half*)(csr + NBKT * MAXB + 64);
    __half*   buf2      = buf1 + (size_t)(n + 1) * F;

    // ---- zero bucket cursors, then single-pass bucket staging ----
    hipMemsetAsync(gcur, 0, NBKT * sizeof(int), stream);
    k_stage<<<NB, 256, 0, stream>>>(src, dst, gcur, stage, E, NBKT);

    // ---- fused: counts + dis + row_start + csr fill + fp16 prep ----
    k_bins<<<NBKT, 512, 0, stream>>>(stage, gcur, (const float4*)x, count,
                                     row_start, dis, csr, (uint2*)buf1,
                                     (uint2*)buf2, n);

    // ---- 3 fused layers (direct-B gather, depth-2 prefetch) ----
    int nb_l = (n + 63) / 64;   // 4 waves/block, 16 rows/wave
    k_layer<<<nb_l, 256, 0, stream>>>(buf1, W1, b1, row_start, count, csr, dis, buf2, n, 1);
    k_layer<<<nb_l, 256, 0, stream>>>(buf2, W2, b2, row_start, count, csr, dis, buf1, n, 1);
    k_layer<<<nb_l, 256, 0, stream>>>(buf1, W3, b3, row_start, count, csr, dis, buf2, n, 0);

    // ---- final linear (row-per-thread, vectorized) ----
    k_final<<<(n + 255) / 256, 256, 0, stream>>>(buf2, Wl, bl, out, n);
}

// Round 10
// 277.754 us; speedup vs baseline: 1.1409x; 1.1210x over previous
//
#include <hip/hip_runtime.h>
#include <hip/hip_fp16.h>

#define F 64
#define CHUNK 2048    // edges per chunk (256 thr x 2 int4 x 4)
#define BN 512        // dst nodes per bucket (power of 2)
#define BSHIFT 9
#define MAXBS 10240   // fixed stage region per bucket (edges); mean 8192, +22 sigma
#define MAXB 11264    // fixed csr region per bucket (padded slots); max ~10.8K
// record = (dstLocal<<17)|src : needs n < 2^17 (n=100000 ok)

typedef int v4i __attribute__((ext_vector_type(4)));
typedef float fx4 __attribute__((ext_vector_type(4)));
typedef float v2f __attribute__((ext_vector_type(2)));
typedef _Float16 h8f __attribute__((ext_vector_type(8)));

union FB8 { uint4 u; h8f h; };
union FX4P { fx4 v; v2f p[2]; };

// ============ single-pass bucket-sorted staging ============
// Fixed per-bucket stage regions (bkt*MAXBS) + one global cursor atomicAdd per
// (block, nonzero bucket). Order within a bucket is arbitrary (agg is a sum).
__global__ __launch_bounds__(256) void k_stage(const int* __restrict__ src,
                                               const int* __restrict__ dst,
                                               int* __restrict__ gcur,
                                               unsigned* __restrict__ stage,
                                               int E, int NBKT) {
    __shared__ int lcnt[256];
    __shared__ int lbase[257];
    __shared__ int obase[256];
    __shared__ int s[256];
    __shared__ unsigned rec[CHUNK];
    __shared__ unsigned char binof[CHUNK];
    int b = blockIdx.x, t = threadIdx.x;
    lcnt[t] = 0;
    __syncthreads();
    const v4i* d4 = (const v4i*)dst;
    const v4i* s4 = (const v4i*)src;
    int g0 = (b * CHUNK) >> 2;
    int E4 = E >> 2;   // E divisible by 4
    int myseg[8], myrank[8];
    unsigned myrec[8];
#pragma unroll
    for (int k = 0; k < 2; ++k) {
        int gi = g0 + k * 256 + t;
        bool ok = gi < E4;
        v4i qd = {0, 0, 0, 0}, qs = {0, 0, 0, 0};
        if (ok) {
            qd = __builtin_nontemporal_load(d4 + gi);
            qs = __builtin_nontemporal_load(s4 + gi);
        }
        int dd[4] = {qd.x, qd.y, qd.z, qd.w};
        int ss[4] = {qs.x, qs.y, qs.z, qs.w};
#pragma unroll
        for (int j = 0; j < 4; ++j) {
            int idx = k * 4 + j;
            myseg[idx] = -1;
            if (ok) {
                int sg = dd[j] >> BSHIFT;
                myseg[idx] = sg;
                myrank[idx] = atomicAdd(&lcnt[sg], 1);
                myrec[idx] = ((unsigned)(dd[j] & (BN - 1)) << 17) | (unsigned)ss[j];
            }
        }
    }
    __syncthreads();
    int v = lcnt[t];
    s[t] = v;
    __syncthreads();
    for (int off = 1; off < 256; off <<= 1) {
        int x = (t >= off) ? s[t - off] : 0;
        __syncthreads();
        s[t] += x;
        __syncthreads();
    }
    lbase[t] = s[t] - v;
    if (t == 255) lbase[256] = s[255];
    obase[t] = 0;
    if (t < NBKT && v > 0) obase[t] = t * MAXBS + atomicAdd(&gcur[t], v);
    __syncthreads();
#pragma unroll
    for (int k = 0; k < 8; ++k) {
        if (myseg[k] >= 0) {
            int p = lbase[myseg[k]] + myrank[k];
            rec[p] = myrec[k];
            binof[p] = (unsigned char)myseg[k];
        }
    }
    __syncthreads();
    int tot = lbase[256];
    for (int j = t; j < tot; j += 256) {
        int sg = binof[j];
        stage[obase[sg] + (j - lbase[sg])] = rec[j];
    }
}

// ============ FUSED: histogram + dis + row_start + csr fill + fp16 prep ============
__global__ __launch_bounds__(512) void k_bins(const unsigned* __restrict__ stage,
        const int* __restrict__ gcur, const float4* __restrict__ x4,
        int* __restrict__ count, int* __restrict__ row_start,
        float* __restrict__ dis, int* __restrict__ csr,
        uint2* __restrict__ hs, uint2* __restrict__ hs2, int n) {
    __shared__ int lc[BN];
    __shared__ int sc[BN];
    __shared__ float fdis[BN];
    __shared__ int buf[MAXB];
    int bkt = blockIdx.x, t = threadIdx.x;
    int nb0 = bkt << BSHIFT;
    lc[t] = 0;
    __syncthreads();
    int r0 = bkt * MAXBS;
    int r1 = r0 + gcur[bkt];
    // histogram
    for (int j = r0 + t; j < r1; j += 512) atomicAdd(&lc[stage[j] >> 17], 1);
    __syncthreads();
    int node = nb0 + t;
    int cv = lc[t];
    int pv = 0;
    float dval = 0.f;
    if (node < n) {
        count[node] = cv;
        dval = rsqrtf((float)(cv + 1));
        dis[node] = dval;
        pv = (cv + 3) & ~3;
    }
    fdis[t] = dval;
    sc[t] = pv;
    __syncthreads();
    for (int off = 1; off < BN; off <<= 1) {
        int x = (t >= off) ? sc[t - off] : 0;
        __syncthreads();
        sc[t] += x;
        __syncthreads();
    }
    int excl = sc[t] - pv;
    int wlen = sc[BN - 1];
    if (node < n) row_start[node] = bkt * MAXB + excl;
    lc[t] = excl;                         // reuse as fill cursor
    for (int j = t; j < wlen && j < MAXB; j += 512) buf[j] = n;   // pad value
    __syncthreads();
    for (int j = r0 + t; j < r1; j += 512) {
        unsigned r = stage[j];
        int p = atomicAdd(&lc[r >> 17], 1);
        if (p < MAXB) buf[p] = (int)(r & 0x1FFFFu);
    }
    __syncthreads();
    int cbase = bkt * MAXB;
    for (int j = t; j < wlen && j < MAXB; j += 512) csr[cbase + j] = buf[j];
    // fp16 prep for this bucket's rows (+ row n of both buffers in last bucket)
    for (int ii = t; ii < (BN << 4); ii += 512) {
        int loc = ii >> 4;
        int node2 = nb0 + loc;
        int c = ii & 15;
        float dv = 0.f;
        float4 v = make_float4(0.f, 0.f, 0.f, 0.f);
        if (node2 < n) { dv = fdis[loc]; v = x4[(size_t)node2 * 16 + c]; }
        __half2 h01 = __floats2half2_rn(dv * v.x, dv * v.y);
        __half2 h23 = __floats2half2_rn(dv * v.z, dv * v.w);
        uint2 u;
        u.x = *(unsigned*)&h01;
        u.y = *(unsigned*)&h23;
        if (node2 <= n) hs[(size_t)node2 * 16 + c] = u;
        if (node2 == n) hs2[(size_t)n * 16 + c] = make_uint2(0u, 0u);
    }
}

// ============ direct-B MFMA aggregation (depth-2) + exact f32 transform ============
// r9 post-mortem: r8/r9's FETCH 150MB (vs r7 81.6) was buf1 losing 128B
// alignment (offset mod 128 = 64) -> every random 128B row gather straddled an
// extra L2 sector. Launcher now 512B-aligns buf1. Body identical to r7/r9.
__global__ __launch_bounds__(256) void k_layer(const __half* __restrict__ hin,
        const float* __restrict__ W, const float* __restrict__ b,
        const int* __restrict__ row_start, const int* __restrict__ count,
        const int* __restrict__ csr, const float* __restrict__ dis,
        __half* __restrict__ hout, int n, int scale_out) {
    __shared__ char lds_all[16384];
    int tid = threadIdx.x;
    int lane = tid & 63;
    int wv = tid >> 6;
    int r0 = (blockIdx.x * 4 + wv) << 4;
    if (r0 >= n) return;
    char* myLds = lds_all + (wv << 12);
    const _Float16* hp = (const _Float16*)hin;

    int r_  = lane & 15;
    int g4  = lane >> 4;
    int l31 = lane & 31;

    int lo = row_start[r0 + r_];
    int cnt_ = count[r0 + r_];
    int hi = lo + ((cnt_ + 3) & ~3);
    int s0 = __shfl(lo, 0);
    int s4 = __shfl(hi, 15);
    int NBb = (s4 - s0 + 31) >> 5;      // 32-slot batches; batch NBb = self
    unsigned deg = (unsigned)(hi - lo);

    fx4 acc0 = {0.f, 0.f, 0.f, 0.f};
    fx4 acc1 = acc0, acc2 = acc0, acc3 = acc0;

    auto ldnodes = [&](int i) -> int {
        if (i < NBb) {
            int slot = s0 + (i << 5) + l31;
            int nd = csr[slot];                 // slack in csr alloc; value clamped
            return (slot < s4) ? nd : n;
        }
        return (l31 < 16) ? (r0 + l31) : n;     // self batch (q>=16 -> zero row)
    };

#define LOADFRAG(F0, F1, F2, F3, NDS) { \
    _Pragma("unroll") \
    for (int j = 0; j < 8; ++j) { \
        int ndj = __shfl((NDS), 8 * g4 + j); \
        const _Float16* rp = hp + (((size_t)(unsigned)ndj) << 6) + r_; \
        F0.h[j] = rp[0]; \
        F1.h[j] = rp[16]; \
        F2.h[j] = rp[32]; \
        F3.h[j] = rp[48]; \
    } \
}

#define SMFMA(TT, F0, F1, F2, F3) { \
    unsigned w[4]; \
    if ((TT) < NBb) { \
        unsigned u0 = (unsigned)(s0 + ((TT) << 5) + (g4 << 3)) - (unsigned)lo; \
        w[0] = ((u0     ) < deg ? 0x3C00u : 0u) | ((u0 + 1u) < deg ? 0x3C000000u : 0u); \
        w[1] = ((u0 + 2u) < deg ? 0x3C00u : 0u) | ((u0 + 3u) < deg ? 0x3C000000u : 0u); \
        w[2] = ((u0 + 4u) < deg ? 0x3C00u : 0u) | ((u0 + 5u) < deg ? 0x3C000000u : 0u); \
        w[3] = ((u0 + 6u) < deg ? 0x3C00u : 0u) | ((u0 + 7u) < deg ? 0x3C000000u : 0u); \
    } else { \
        int k0 = g4 << 3; \
        w[0] = ((k0    ) == r_ ? 0x3C00u : 0u) | ((k0 + 1) == r_ ? 0x3C000000u : 0u); \
        w[1] = ((k0 + 2) == r_ ? 0x3C00u : 0u) | ((k0 + 3) == r_ ? 0x3C000000u : 0u); \
        w[2] = ((k0 + 4) == r_ ? 0x3C00u : 0u) | ((k0 + 5) == r_ ? 0x3C000000u : 0u); \
        w[3] = ((k0 + 6) == r_ ? 0x3C00u : 0u) | ((k0 + 7) == r_ ? 0x3C000000u : 0u); \
    } \
    FB8 af; af.u = make_uint4(w[0], w[1], w[2], w[3]); \
    acc0 = __builtin_amdgcn_mfma_f32_16x16x32_f16(af.h, F0.h, acc0, 0, 0, 0); \
    acc1 = __builtin_amdgcn_mfma_f32_16x16x32_f16(af.h, F1.h, acc1, 0, 0, 0); \
    acc2 = __builtin_amdgcn_mfma_f32_16x16x32_f16(af.h, F2.h, acc2, 0, 0, 0); \
    acc3 = __builtin_amdgcn_mfma_f32_16x16x32_f16(af.h, F3.h, acc3, 0, 0, 0); \
}

    FB8 A0, A1, A2, A3, B0, B1, B2, B3;
    int ndA, ndB;
    {
        int nd0 = ldnodes(0);
        LOADFRAG(A0, A1, A2, A3, nd0)      // B(0)
        ndA = ldnodes(1);                  // nodes(t+1)
        ndB = ldnodes(2);                  // nodes(t+2)
    }

    for (int t = 0; ; t += 2) {
        LOADFRAG(B0, B1, B2, B3, ndA)      // issue B(t+1) gathers
        ndA = ldnodes(t + 3);
        SMFMA(t, A0, A1, A2, A3)
        if (t + 1 > NBb) break;
        LOADFRAG(A0, A1, A2, A3, ndB)      // issue B(t+2) gathers
        ndB = ldnodes(t + 4);
        SMFMA(t + 1, B0, B1, B2, B3)
        if (t + 2 > NBb) break;
    }
#undef LOADFRAG
#undef SMFMA

    // ---- dump acc (f32, exact) to T[64 f][16 r]; lane holds D[4g4+v][16S+r_] ----
    float* T = (float*)myLds;
#define TSTORE(S, A) { \
    int fb_ = ((16 * (S) + r_) << 4) + (g4 << 2); \
    *(fx4*)(T + fb_) = A; }
    TSTORE(0, acc0) TSTORE(1, acc1) TSTORE(2, acc2) TSTORE(3, acc3)
#undef TSTORE

    // ---- exact f32 transform (pk-fma): lane = output column o, 16 rows ----
    float bb_ = b[lane];
    v2f yv2[8];
#pragma unroll
    for (int k = 0; k < 8; ++k) { yv2[k].x = 0.f; yv2[k].y = 0.f; }
    const float* Wp = W + lane;
#pragma unroll 4
    for (int f = 0; f < 64; ++f) {
        float w = Wp[f << 6];                   // W[f][lane], coalesced
        v2f wv; wv.x = w; wv.y = w;
        const float* Tf = T + (f << 4);
        FX4P d0, d1, d2, d3;
        d0.v = *(const fx4*)(Tf);               // uniform addr -> LDS broadcast
        d1.v = *(const fx4*)(Tf + 4);
        d2.v = *(const fx4*)(Tf + 8);
        d3.v = *(const fx4*)(Tf + 12);
        yv2[0] += d0.p[0] * wv;  yv2[1] += d0.p[1] * wv;
        yv2[2] += d1.p[0] * wv;  yv2[3] += d1.p[1] * wv;
        yv2[4] += d2.p[0] * wv;  yv2[5] += d2.p[1] * wv;
        yv2[6] += d3.p[0] * wv;  yv2[7] += d3.p[1] * wv;
    }

#pragma unroll
    for (int r = 0; r < 16; ++r) {
        float yvr = (r & 1) ? yv2[r >> 1].y : yv2[r >> 1].x;
        float dd = dis[r0 + r];
        float y = fmaxf(yvr * dd + bb_, 0.f);
        if (scale_out) y *= dd;
        hout[((size_t)(r0 + r) << 6) + lane] = __float2half(y);
    }
}

// ============ final 64->8 linear: row-per-thread, uint2 vector loads ============
__global__ __launch_bounds__(256) void k_final(const __half* __restrict__ h,
                                               const float* __restrict__ Wl,
                                               const float* __restrict__ bl,
                                               float* __restrict__ out, int n) {
    __shared__ float Ws[F * 8];
    __shared__ float bs[8];
    int tid = threadIdx.x;
    Ws[tid] = Wl[tid];
    Ws[tid + 256] = Wl[tid + 256];
    if (tid < 8) bs[tid] = bl[tid];
    __syncthreads();
    int row = blockIdx.x * 256 + tid;
    if (row >= n) return;
    const uint2* hr = (const uint2*)(h + (size_t)row * F);
    float acc[8];
#pragma unroll
    for (int o = 0; o < 8; ++o) acc[o] = bs[o];
#pragma unroll
    for (int k4 = 0; k4 < 16; ++k4) {
        uint2 u = hr[k4];
        float2 f01 = __half22float2(*(__half2*)&u.x);
        float2 f23 = __half22float2(*(__half2*)&u.y);
        const float* w0 = Ws + (k4 * 4) * 8;
#pragma unroll
        for (int o = 0; o < 8; ++o) {
            float a = acc[o];
            a = fmaf(f01.x, w0[o], a);
            a = fmaf(f01.y, w0[8 + o], a);
            a = fmaf(f23.x, w0[16 + o], a);
            a = fmaf(f23.y, w0[24 + o], a);
            acc[o] = a;
        }
    }
    float4* op = (float4*)(out + (size_t)row * 8);
    op[0] = make_float4(acc[0], acc[1], acc[2], acc[3]);
    op[1] = make_float4(acc[4], acc[5], acc[6], acc[7]);
}

extern "C" void kernel_launch(void* const* d_in, const int* in_sizes, int n_in,
                              void* d_out, int out_size, void* d_ws, size_t ws_size,
                              hipStream_t stream) {
    const float* x  = (const float*)d_in[0];
    const int*   ei = (const int*)d_in[1];
    const float* W1 = (const float*)d_in[2];
    const float* b1 = (const float*)d_in[3];
    const float* W2 = (const float*)d_in[4];
    const float* b2 = (const float*)d_in[5];
    const float* W3 = (const float*)d_in[6];
    const float* b3 = (const float*)d_in[7];
    const float* Wl = (const float*)d_in[8];
    const float* bl = (const float*)d_in[9];
    float* out = (float*)d_out;

    int n = in_sizes[0] / F;   // 100000 (n % 16 == 0, n < 2^17)
    int E = in_sizes[1] / 2;   // 1600000 (divisible by 4)
    const int* src = ei;
    const int* dst = ei + E;

    int np   = (n + 256) & ~255;              // >= n+1, multiple of 256
    int NB   = (E + CHUNK - 1) / CHUNK;       // 782 chunks
    int NBKT = (n + BN - 1) >> BSHIFT;        // 196 buckets (<=256)

    // workspace layout (~44 MB); buf1 512B-ALIGNED (r9 lesson: rows are 128B,
    // a 64B-misaligned buf1 doubles L2-sector traffic on random gathers)
    int*      count     = (int*)d_ws;
    int*      row_start = count + np;
    int*      gcur      = row_start + np;       // 196 -> pad 272
    float*    dis       = (float*)(gcur + 272);
    unsigned* stage     = (unsigned*)(dis + np);  // NBKT*MAXBS
    int*      csr       = (int*)(stage + NBKT * MAXBS);   // NBKT*MAXB + slack
    size_t    boff      = (size_t)((char*)(csr + NBKT * MAXB + 64) - (char*)d_ws);
    boff = (boff + 511) & ~(size_t)511;
    __half*   buf1      = (__half*)((char*)d_ws + boff);
    __half*   buf2      = buf1 + (size_t)(n + 1) * F;

    // ---- zero bucket cursors, then single-pass bucket staging ----
    hipMemsetAsync(gcur, 0, NBKT * sizeof(int), stream);
    k_stage<<<NB, 256, 0, stream>>>(src, dst, gcur, stage, E, NBKT);

    // ---- fused: counts + dis + row_start + csr fill + fp16 prep ----
    k_bins<<<NBKT, 512, 0, stream>>>(stage, gcur, (const float4*)x, count,
                                     row_start, dis, csr, (uint2*)buf1,
                                     (uint2*)buf2, n);

    // ---- 3 fused layers (direct-B gather, depth-2 prefetch) ----
    int nb_l = (n + 63) / 64;   // 4 waves/block, 16 rows/wave
    k_layer<<<nb_l, 256, 0, stream>>>(buf1, W1, b1, row_start, count, csr, dis, buf2, n, 1);
    k_layer<<<nb_l, 256, 0, stream>>>(buf2, W2, b2, row_start, count, csr, dis, buf1, n, 1);
    k_layer<<<nb_l, 256, 0, stream>>>(buf1, W3, b3, row_start, count, csr, dis, buf2, n, 0);

    // ---- final linear (row-per-thread, vectorized) ----
    k_final<<<(n + 255) / 256, 256, 0, stream>>>(buf2, Wl, bl, out, n);
}